// Round 5
// baseline (327.186 us; speedup 1.0000x reference)
//
#include <hip/hip_runtime.h>
#include <hip/hip_bf16.h>

typedef __bf16 bf16x8 __attribute__((ext_vector_type(8)));
typedef float  f32x4  __attribute__((ext_vector_type(4)));

#define MFMA16(a, b, c) __builtin_amdgcn_mfma_f32_16x16x32_bf16((a), (b), (c), 0, 0, 0)

// exp2 -> single v_exp_f32
__device__ __forceinline__ float fast_exp2(float x) {
#if __has_builtin(__builtin_amdgcn_exp2f)
    return __builtin_amdgcn_exp2f(x);
#else
    return exp2f(x);
#endif
}

// async global->LDS, 16B per lane; lds base must be wave-uniform.
__device__ __forceinline__ void async16(void* lds, const void* g) {
    __builtin_amdgcn_global_load_lds(
        (const __attribute__((address_space(1))) unsigned int*)g,
        (__attribute__((address_space(3))) unsigned int*)lds, 16, 0, 0);
}

// ---------------- fused transpose+convert: 6 jobs, W[K,N] f32 -> WT[N,K] bf16 ----------------
__device__ __forceinline__ void tconv_tile(const float* __restrict__ W,
                                           __bf16* __restrict__ WT,
                                           int K, int N, int id, int nbx,
                                           __bf16 (*t)[65]) {
    int n0 = (id % nbx) * 64, k0 = (id / nbx) * 64;
    int tx = threadIdx.x & 63, ty = threadIdx.x >> 6;
#pragma unroll
    for (int r = ty; r < 64; r += 4)
        t[r][tx] = (__bf16)W[(size_t)(k0 + r) * N + n0 + tx];
    __syncthreads();
#pragma unroll
    for (int rr = ty; rr < 64; rr += 4)
        WT[(size_t)(n0 + rr) * K + k0 + tx] = t[tx][rr];
}

__global__ __launch_bounds__(256) void tconv6_kernel(
    const float* W0, __bf16* T0, const float* W1, __bf16* T1,
    const float* W2, __bf16* T2, const float* W3, __bf16* T3,
    const float* W4, __bf16* T4, const float* W5, __bf16* T5) {
    __shared__ __bf16 t[64][65];
    int id = blockIdx.x;
    // job block counts: 128,256,128,128,192,128 (cum 128,384,512,640,832,960)
    if (id < 128)      tconv_tile(W0, T0, 1024, 512,  id,       8,  t);
    else if (id < 384) tconv_tile(W1, T1, 1024, 1024, id - 128, 16, t);
    else if (id < 512) tconv_tile(W2, T2, 512,  1024, id - 384, 16, t);
    else if (id < 640) tconv_tile(W3, T3, 1024, 512,  id - 512, 8,  t);
    else if (id < 832) tconv_tile(W4, T4, 768,  1024, id - 640, 16, t);
    else               tconv_tile(W5, T5, 512,  1024, id - 832, 16, t);
}

// ---------------- LayerNorm body ----------------
template <int C>
__device__ __forceinline__ void ln_body(const float* __restrict__ xr,
                                        const float* __restrict__ g,
                                        const float* __restrict__ b,
                                        __bf16* __restrict__ orow,
                                        float* p1, float* p2) {
    constexpr int NP = (C == 1024) ? 4 : 3;
    float v[NP], s1 = 0.f, s2 = 0.f;
    if constexpr (C == 1024) {
        float4 f = *(const float4*)&xr[threadIdx.x * 4];
        v[0] = f.x; v[1] = f.y; v[2] = f.z; v[3] = f.w;
#pragma unroll
        for (int i = 0; i < 4; i++) { s1 += v[i]; s2 += v[i] * v[i]; }
    } else {
#pragma unroll
        for (int i = 0; i < 3; i++) {
            v[i] = xr[threadIdx.x + i * 256];
            s1 += v[i]; s2 += v[i] * v[i];
        }
    }
#pragma unroll
    for (int off = 1; off < 64; off <<= 1) {
        s1 += __shfl_xor(s1, off);
        s2 += __shfl_xor(s2, off);
    }
    int wave = threadIdx.x >> 6;
    if ((threadIdx.x & 63) == 0) { p1[wave] = s1; p2[wave] = s2; }
    __syncthreads();
    s1 = p1[0] + p1[1] + p1[2] + p1[3];
    s2 = p2[0] + p2[1] + p2[2] + p2[3];
    float mean = s1 / C;
    float rstd = rsqrtf(s2 / C - mean * mean + 1e-5f);
    if constexpr (C == 1024) {
        union { __bf16 h[4]; unsigned long long u; } pk;
#pragma unroll
        for (int i = 0; i < 4; i++) {
            int c = threadIdx.x * 4 + i;
            pk.h[i] = (__bf16)((v[i] - mean) * rstd * g[c] + b[c]);
        }
        *(unsigned long long*)&orow[threadIdx.x * 4] = pk.u;
    } else {
#pragma unroll
        for (int i = 0; i < 3; i++) {
            int c = threadIdx.x + i * 256;
            orow[c] = (__bf16)((v[i] - mean) * rstd * g[c] + b[c]);
        }
    }
}

// dual LayerNorm (shared row stats) for self-attn: x -> (g1,b1)->o1, (g2,b2)->o2
__global__ __launch_bounds__(256) void ln2_kernel(const float* __restrict__ x,
                                                  const float* __restrict__ g1,
                                                  const float* __restrict__ b1,
                                                  const float* __restrict__ g2,
                                                  const float* __restrict__ b2,
                                                  __bf16* __restrict__ o1,
                                                  __bf16* __restrict__ o2) {
    constexpr int C = 1024;
    int row = blockIdx.x;
    const float* xr = x + (size_t)row * C;
    float4 f = *(const float4*)&xr[threadIdx.x * 4];
    float v[4] = {f.x, f.y, f.z, f.w};
    float s1 = 0.f, s2 = 0.f;
#pragma unroll
    for (int i = 0; i < 4; i++) { s1 += v[i]; s2 += v[i] * v[i]; }
#pragma unroll
    for (int off = 1; off < 64; off <<= 1) {
        s1 += __shfl_xor(s1, off);
        s2 += __shfl_xor(s2, off);
    }
    __shared__ float p1[4], p2[4];
    int wave = threadIdx.x >> 6;
    if ((threadIdx.x & 63) == 0) { p1[wave] = s1; p2[wave] = s2; }
    __syncthreads();
    s1 = p1[0] + p1[1] + p1[2] + p1[3];
    s2 = p2[0] + p2[1] + p2[2] + p2[3];
    float mean = s1 / C;
    float rstd = rsqrtf(s2 / C - mean * mean + 1e-5f);
    union { __bf16 h[4]; unsigned long long u; } pk1, pk2;
#pragma unroll
    for (int i = 0; i < 4; i++) {
        int c = threadIdx.x * 4 + i;
        float nv = (v[i] - mean) * rstd;
        pk1.h[i] = (__bf16)(nv * g1[c] + b1[c]);
        pk2.h[i] = (__bf16)(nv * g2[c] + b2[c]);
    }
    *(unsigned long long*)&o1[(size_t)row * C + threadIdx.x * 4] = pk1.u;
    *(unsigned long long*)&o2[(size_t)row * C + threadIdx.x * 4] = pk2.u;
}

// fused cross-stage LNs: blocks [0,8192) -> ln1024(x1), [8192,10240) -> ln768(ctx)
__global__ __launch_bounds__(256) void ln_cross_kernel(
    const float* __restrict__ x1, const float* __restrict__ g1, const float* __restrict__ b1,
    __bf16* __restrict__ o1,
    const float* __restrict__ ctx, const float* __restrict__ g2, const float* __restrict__ b2,
    __bf16* __restrict__ o2, int rows1) {
    __shared__ float p1[4], p2[4];
    int id = blockIdx.x;
    if (id < rows1) {
        ln_body<1024>(x1 + (size_t)id * 1024, g1, b1, o1 + (size_t)id * 1024, p1, p2);
    } else {
        int row = id - rows1;
        ln_body<768>(ctx + (size_t)row * 768, g2, b2, o2 + (size_t)row * 768, p1, p2);
    }
}

// ---------------- GEMM core (BK=64): C[M,N] = A[M,K] @ BT[N,K]^T ----------------
// LDS per tile: 128 rows x 64 elems (16KB each), 16B chunks swizzled: chunk c at slot c^(r&7).
// EPI 0: store bf16 (acc*scale).  EPI 1: store f32 = acc + bias[col] + res[row,col]
template <int EPI>
__device__ __forceinline__ void gemm_core(const __bf16* __restrict__ A,
                                          const __bf16* __restrict__ BT,
                                          void* __restrict__ Cout,
                                          int N, int K, int bm, int bn,
                                          const float* __restrict__ bias,
                                          const float* __restrict__ res,
                                          float scale,
                                          __bf16* Al, __bf16* Bl) {
    int tid = threadIdx.x;
    int lane = tid & 63, wave = tid >> 6;
    int quad = lane >> 4, l15 = lane & 15;
    int wm = wave >> 1, wn = wave & 1;
    const __bf16* Ab = A + (size_t)(bm * 128) * K;
    const __bf16* Bb = BT + (size_t)(bn * 128) * K;
    f32x4 acc[4][4] = {};
    for (int k0 = 0; k0 < K; k0 += 64) {
#pragma unroll
        for (int j = 0; j < 4; j++) {
            int sbase = wave * 256 + j * 64;
            int s = sbase + lane;
            int r = s >> 3, c = (s & 7) ^ (r & 7);
            async16((char*)Al + sbase * 16, &Ab[(size_t)r * K + k0 + c * 8]);
            async16((char*)Bl + sbase * 16, &Bb[(size_t)r * K + k0 + c * 8]);
        }
        __syncthreads();
#pragma unroll
        for (int ks = 0; ks < 2; ks++) {
            bf16x8 a[4], b[4];
#pragma unroll
            for (int i = 0; i < 4; i++) {
                int row = wm * 64 + i * 16 + l15;
                a[i] = *(const bf16x8*)&Al[row * 64 + ((ks * 4 + quad) ^ (row & 7)) * 8];
            }
#pragma unroll
            for (int t = 0; t < 4; t++) {
                int row = wn * 64 + t * 16 + l15;
                b[t] = *(const bf16x8*)&Bl[row * 64 + ((ks * 4 + quad) ^ (row & 7)) * 8];
            }
#pragma unroll
            for (int i = 0; i < 4; i++)
#pragma unroll
                for (int t = 0; t < 4; t++) acc[i][t] = MFMA16(a[i], b[t], acc[i][t]);
        }
        __syncthreads();
    }
#pragma unroll
    for (int i = 0; i < 4; i++) {
#pragma unroll
        for (int t = 0; t < 4; t++) {
#pragma unroll
            for (int r = 0; r < 4; r++) {
                int row = bm * 128 + wm * 64 + i * 16 + quad * 4 + r;
                int col = bn * 128 + wn * 64 + t * 16 + l15;
                float vv = acc[i][t][r];
                if (EPI == 0) {
                    ((__bf16*)Cout)[(size_t)row * N + col] = (__bf16)(vv * scale);
                } else {
                    ((float*)Cout)[(size_t)row * N + col] =
                        vv + bias[col] + res[(size_t)row * N + col];
                }
            }
        }
    }
}

template <int EPI>
__global__ __launch_bounds__(256) void gemm_bt(const __bf16* __restrict__ A,
                                               const __bf16* __restrict__ BT,
                                               void* __restrict__ Cout,
                                               int M, int N, int K,
                                               const float* __restrict__ bias,
                                               const float* __restrict__ res) {
    __shared__ __align__(16) __bf16 Al[128 * 64];
    __shared__ __align__(16) __bf16 Bl[128 * 64];
    gemm_core<EPI>(A, BT, Cout, N, K, blockIdx.x, blockIdx.y, bias, res, 1.0f, Al, Bl);
}

// Fused 3-job GEMM (all EPI=0 bf16 out, per-job output scale).
__global__ __launch_bounds__(256) void gemm_fused3(
    const __bf16* A0, const __bf16* B0, __bf16* C0, int N0, int K0, int nbn0, float sc0,
    const __bf16* A1, const __bf16* B1, __bf16* C1, int N1, int K1, int nbn1, float sc1,
    const __bf16* A2, const __bf16* B2, __bf16* C2, int N2, int K2, int nbn2, float sc2,
    int c0, int c1) {
    __shared__ __align__(16) __bf16 Al[128 * 64];
    __shared__ __align__(16) __bf16 Bl[128 * 64];
    int id = blockIdx.x;
    if (id < c0) {
        gemm_core<0>(A0, B0, C0, N0, K0, id / nbn0, id % nbn0, nullptr, nullptr, sc0, Al, Bl);
    } else if (id < c1) {
        id -= c0;
        gemm_core<0>(A1, B1, C1, N1, K1, id / nbn1, id % nbn1, nullptr, nullptr, sc1, Al, Bl);
    } else {
        id -= c1;
        gemm_core<0>(A2, B2, C2, N2, K2, id / nbn2, id % nbn2, nullptr, nullptr, sc2, Al, Bl);
    }
}

// ---------------- flash attention v5: paired k-tiles, 128-row q-tile ----------------
// Postmortems: v2 LDS-bound (84%); v4 (32q/wave) cut LDS to ~55% but occupancy fell
// to 2 blocks/CU (grid 512) -> latency-bound, flat. v5: grid pins us at 2 blocks/CU
// anyway, so spend the free LDS (80KB) on a PAIR of k-tiles per barrier: two
// independent St->softmax->PV chains back-to-back between barriers (in-wave ILP;
// St(B) overlaps PV(A) stalls), and half the barriers (16/dispatch). P region
// reused A->B (DS ops are wave-ordered; compiler sees the alias).
// q pre-scaled by 0.125*log2(e) in its projection epilogue.
__global__ __launch_bounds__(256) void flash_kernel(const __bf16* __restrict__ q,
                                                    const __bf16* __restrict__ kb,
                                                    const __bf16* __restrict__ vt,
                                                    __bf16* __restrict__ out,
                                                    int n, int m) {
    __shared__ __align__(16) __bf16 Ks[2][2][64 * 64];   // [pair buf][tile in pair]
    __shared__ __align__(16) __bf16 VTs[2][2][64 * 64];
    __shared__ __align__(16) __bf16 Ps[4][32 * 64];      // per-wave P region (4KB)
    int tid = threadIdx.x;
    int lane = tid & 63, w = tid >> 6;
    int quad = lane >> 4, l15 = lane & 15;
    int qt = blockIdx.x, h = blockIdx.y, b = blockIdx.z;
    const size_t BM = (size_t)gridDim.z * m;

    // Q fragments: this wave's 32 q-rows (2 u-tiles of 16)
    const __bf16* qbase = q + (size_t)(b * n + qt * 128 + w * 32) * 512 + h * 64;
    bf16x8 qf[2][2];
#pragma unroll
    for (int s = 0; s < 2; s++)
#pragma unroll
        for (int u = 0; u < 2; u++)
            qf[s][u] = *(const bf16x8*)&qbase[(u * 16 + l15) * 512 + s * 32 + quad * 8];

    // staging geometry: wave fills LDS slots [w*128, w*128+128) (two async16 per array)
    int s0 = w * 128 + lane, s1 = s0 + 64;
    int r0 = s0 >> 3, c0 = (s0 & 7) ^ (r0 & 7);
    int r1 = s1 >> 3, c1 = (s1 & 7) ^ (r1 & 7);
    const int sb0 = (w * 128) * 16, sb1 = sb0 + 64 * 16;  // wave-uniform LDS byte offsets
    const __bf16* ksrc0 = &kb[(size_t)(b * m + r0) * 512 + h * 64 + (size_t)c0 * 8];
    const __bf16* ksrc1 = &kb[(size_t)(b * m + r1) * 512 + h * 64 + (size_t)c1 * 8];
    const __bf16* vsrc0 = &vt[(size_t)(h * 64 + r0) * BM + b * m + (size_t)c0 * 8];
    const __bf16* vsrc1 = &vt[(size_t)(h * 64 + r1) * BM + b * m + (size_t)c1 * 8];
    const size_t kadv = (size_t)64 * 512;  // advance 64 K-rows per tile
    const int vadv = 64;                   // advance 64 VT-cols per tile

    f32x4 acc[2][4] = {};                  // O [u qtile][t2 dtile]
    float lp[2] = {0.f, 0.f};
    __bf16* Pw = Ps[w];
    int npair = m / 128;

    // prologue: stage tiles 0,1 into pair buffer 0
#pragma unroll
    for (int tt = 0; tt < 2; tt++) {
        async16((char*)Ks[0][tt] + sb0, ksrc0);
        async16((char*)Ks[0][tt] + sb1, ksrc1);
        async16((char*)VTs[0][tt] + sb0, vsrc0);
        async16((char*)VTs[0][tt] + sb1, vsrc1);
        ksrc0 += kadv; ksrc1 += kadv; vsrc0 += vadv; vsrc1 += vadv;
    }

    for (int j = 0; j < npair; j++) {
        int pb = j & 1;
        // drains vmcnt -> pair buf[pb] ready; fences other waves off buf[pb^1]
        __syncthreads();
        if (j + 1 < npair) {
#pragma unroll
            for (int tt = 0; tt < 2; tt++) {
                async16((char*)Ks[pb ^ 1][tt] + sb0, ksrc0);
                async16((char*)Ks[pb ^ 1][tt] + sb1, ksrc1);
                async16((char*)VTs[pb ^ 1][tt] + sb0, vsrc0);
                async16((char*)VTs[pb ^ 1][tt] + sb1, vsrc1);
                ksrc0 += kadv; ksrc1 += kadv; vsrc0 += vadv; vsrc1 += vadv;
            }
        }

#pragma unroll
        for (int tt = 0; tt < 2; tt++) {
            const __bf16* Kc = Ks[pb][tt];
            const __bf16* Vc = VTs[pb][tt];

            // St = K @ Q^T: each K fragment read once, used for both u-tiles
#pragma unroll
            for (int t = 0; t < 4; t++) {
                int krow = t * 16 + l15;
                bf16x8 ak0 = *(const bf16x8*)&Kc[krow * 64 + ((quad) ^ (krow & 7)) * 8];
                bf16x8 ak1 = *(const bf16x8*)&Kc[krow * 64 + ((4 + quad) ^ (krow & 7)) * 8];
                f32x4 sc[2] = {};
#pragma unroll
                for (int u = 0; u < 2; u++) {
                    sc[u] = MFMA16(ak0, qf[0][u], sc[u]);
                    sc[u] = MFMA16(ak1, qf[1][u], sc[u]);
                }
#pragma unroll
                for (int u = 0; u < 2; u++) {
                    float e0 = fast_exp2(sc[u][0]);
                    float e1 = fast_exp2(sc[u][1]);
                    float e2 = fast_exp2(sc[u][2]);
                    float e3 = fast_exp2(sc[u][3]);
                    lp[u] += (e0 + e1) + (e2 + e3);
                    union { __bf16 h[4]; unsigned long long uu; } pk;
                    pk.h[0] = (__bf16)e0; pk.h[1] = (__bf16)e1;
                    pk.h[2] = (__bf16)e2; pk.h[3] = (__bf16)e3;
                    int qp = u * 16 + l15;
                    int chunk = t * 2 + (quad >> 1);
                    int off = qp * 64 + (chunk ^ (qp & 7)) * 8 + (quad & 1) * 4;
                    *(unsigned long long*)&Pw[off] = pk.uu;
                }
            }

            // O += P @ V  (P region wave-private: no barrier, lgkmcnt dep only)
#pragma unroll
            for (int s = 0; s < 2; s++) {
                bf16x8 ap[2];
#pragma unroll
                for (int u = 0; u < 2; u++) {
                    int qp = u * 16 + l15;
                    ap[u] = *(const bf16x8*)&Pw[qp * 64 + ((s * 4 + quad) ^ (qp & 7)) * 8];
                }
#pragma unroll
                for (int t2 = 0; t2 < 4; t2++) {
                    int drow = t2 * 16 + l15;
                    int jv = (s * 4 + quad) ^ (drow & 7);
                    bf16x8 bv = *(const bf16x8*)&Vc[drow * 64 + jv * 8];
#pragma unroll
                    for (int u = 0; u < 2; u++)
                        acc[u][t2] = MFMA16(ap[u], bv, acc[u][t2]);
                }
            }
        }
    }

    // ---- epilogue: l-reduce over quads, scale, store ----
#pragma unroll
    for (int u = 0; u < 2; u++) {
        lp[u] += __shfl_xor(lp[u], 16);
        lp[u] += __shfl_xor(lp[u], 32);
    }
    float rinv0 = 1.0f / lp[0];
    float rinv1 = 1.0f / lp[1];
#pragma unroll
    for (int u = 0; u < 2; u++) {
#pragma unroll
        for (int r = 0; r < 4; r++) {
            float rl = __shfl(u == 0 ? rinv0 : rinv1, quad * 4 + r);
            int row = b * n + qt * 128 + w * 32 + u * 16 + quad * 4 + r;
#pragma unroll
            for (int t2 = 0; t2 < 4; t2++)
                out[(size_t)row * 512 + h * 64 + t2 * 16 + l15] =
                    (__bf16)(acc[u][t2][r] * rl);
        }
    }
}

extern "C" void kernel_launch(void* const* d_in, const int* in_sizes, int n_in,
                              void* d_out, int out_size, void* d_ws, size_t ws_size,
                              hipStream_t stream) {
    const float* x      = (const float*)d_in[0];
    const float* ctx    = (const float*)d_in[1];
    const float* sa_ng  = (const float*)d_in[2];
    const float* sa_nb  = (const float*)d_in[3];
    const float* sa_ncg = (const float*)d_in[4];
    const float* sa_ncb = (const float*)d_in[5];
    const float* sa_wq  = (const float*)d_in[6];
    const float* sa_wkv = (const float*)d_in[7];
    const float* sa_wo  = (const float*)d_in[8];
    const float* sa_bo  = (const float*)d_in[9];
    const float* ca_ng  = (const float*)d_in[10];
    const float* ca_nb  = (const float*)d_in[11];
    const float* ca_ncg = (const float*)d_in[12];
    const float* ca_ncb = (const float*)d_in[13];
    const float* ca_wq  = (const float*)d_in[14];
    const float* ca_wkv = (const float*)d_in[15];
    const float* ca_wo  = (const float*)d_in[16];
    const float* ca_bo  = (const float*)d_in[17];
    float* out = (float*)d_out;

    const int B = 4, N = 2048, M = 512, F = 1024, CF = 768, MID = 512;
    const int ROWS = B * N;   // 8192
    const int CROWS = B * M;  // 2048
    const float QSCALE = 0.125f * 1.4426950408889634f;  // attn scale * log2(e)

    char* ws = (char*)d_ws;
    size_t off = 0;
    auto alloc = [&](size_t bytes) {
        void* p = ws + off;
        off = (off + bytes + 255) & ~(size_t)255;
        return p;
    };
    __bf16* wqT   = (__bf16*)alloc((size_t)MID * F * 2);
    __bf16* wkvT  = (__bf16*)alloc((size_t)(2 * MID) * F * 2);
    __bf16* woT   = (__bf16*)alloc((size_t)F * MID * 2);
    __bf16* cwqT  = (__bf16*)alloc((size_t)MID * F * 2);
    __bf16* cwkvT = (__bf16*)alloc((size_t)(2 * MID) * CF * 2);
    __bf16* cwoT  = (__bf16*)alloc((size_t)F * MID * 2);
    __bf16* xn1   = (__bf16*)alloc((size_t)ROWS * F * 2);
    __bf16* xn2   = (__bf16*)alloc((size_t)ROWS * F * 2);
    __bf16* qb    = (__bf16*)alloc((size_t)ROWS * MID * 2);
    __bf16* kb    = (__bf16*)alloc((size_t)ROWS * MID * 2);
    __bf16* vt    = (__bf16*)alloc((size_t)MID * ROWS * 2);
    __bf16* ao    = (__bf16*)alloc((size_t)ROWS * MID * 2);
    float*  x1    = (float*)alloc((size_t)ROWS * F * 4);
    (void)ws_size; (void)in_sizes; (void)n_in; (void)out_size;

    dim3 blk(256);

    tconv6_kernel<<<dim3(960), blk, 0, stream>>>(
        sa_wq, wqT, sa_wkv, wkvT, sa_wo, woT, ca_wq, cwqT, ca_wkv, cwkvT, ca_wo, cwoT);

    // ---- self-attention ----
    ln2_kernel<<<dim3(ROWS), blk, 0, stream>>>(x, sa_ng, sa_nb, sa_ncg, sa_ncb, xn1, xn2);
    {
        int c0 = (ROWS / 128) * (MID / 128);          // q: 256
        int c1 = c0 + (ROWS / 128) * (MID / 128);     // k: 256
        int c2 = c1 + (MID / 128) * (ROWS / 128);     // vt: 256
        gemm_fused3<<<dim3(c2), blk, 0, stream>>>(
            xn1, wqT, qb, MID, F, MID / 128, QSCALE,
            xn2, wkvT, kb, MID, F, MID / 128, 1.0f,
            wkvT + (size_t)MID * F, xn2, vt, ROWS, F, ROWS / 128, 1.0f,
            c0, c1);
    }
    flash_kernel<<<dim3(N / 128, 8, B), blk, 0, stream>>>(qb, kb, vt, ao, N, N);
    gemm_bt<1><<<dim3(ROWS / 128, F / 128), blk, 0, stream>>>(
        ao, woT, x1, ROWS, F, MID, sa_bo, x);

    // ---- cross-attention ----
    ln_cross_kernel<<<dim3(ROWS + CROWS), blk, 0, stream>>>(
        x1, ca_ng, ca_nb, xn1, ctx, ca_ncg, ca_ncb, xn2, ROWS);
    {
        int c0 = (ROWS / 128) * (MID / 128);          // q: 256
        int c1 = c0 + (CROWS / 128) * (MID / 128);    // k: 64
        int c2 = c1 + (MID / 128) * (CROWS / 128);    // vt: 64
        gemm_fused3<<<dim3(c2), blk, 0, stream>>>(
            xn1, cwqT, qb, MID, F, MID / 128, QSCALE,
            xn2, cwkvT, kb, MID, CF, MID / 128, 1.0f,
            cwkvT + (size_t)MID * CF, xn2, vt, CROWS, CF, CROWS / 128, 1.0f,
            c0, c1);
    }
    flash_kernel<<<dim3(N / 128, 8, B), blk, 0, stream>>>(qb, kb, vt, ao, N, M);
    gemm_bt<1><<<dim3(ROWS / 128, F / 128), blk, 0, stream>>>(
        ao, cwoT, out, ROWS, F, MID, ca_bo, x1);
}

// Round 6
// 306.189 us; speedup vs baseline: 1.0686x; 1.0686x over previous
//
#include <hip/hip_runtime.h>
#include <hip/hip_bf16.h>

typedef __bf16 bf16x8 __attribute__((ext_vector_type(8)));
typedef float  f32x4  __attribute__((ext_vector_type(4)));

#define MFMA16(a, b, c) __builtin_amdgcn_mfma_f32_16x16x32_bf16((a), (b), (c), 0, 0, 0)

// exp2 -> single v_exp_f32
__device__ __forceinline__ float fast_exp2(float x) {
#if __has_builtin(__builtin_amdgcn_exp2f)
    return __builtin_amdgcn_exp2f(x);
#else
    return exp2f(x);
#endif
}

// async global->LDS, 16B per lane; lds base must be wave-uniform.
__device__ __forceinline__ void async16(void* lds, const void* g) {
    __builtin_amdgcn_global_load_lds(
        (const __attribute__((address_space(1))) unsigned int*)g,
        (__attribute__((address_space(3))) unsigned int*)lds, 16, 0, 0);
}

// pack two f32 -> 2x bf16 in one u32 (low word = lo)
__device__ __forceinline__ unsigned cvt_pk_bf16(float lo, float hi) {
    unsigned r;
    asm("v_cvt_pk_bf16_f32 %0, %1, %2" : "=v"(r) : "v"(lo), "v"(hi));
    return r;
}
// gfx950 lane-group swaps: pl32 swaps a.groups{2,3} <-> b.groups{0,1} (16-lane groups)
__device__ __forceinline__ void pl32(unsigned& a, unsigned& b) {
    asm volatile("v_permlane32_swap_b32 %0, %1" : "+v"(a), "+v"(b));
}
// pl16 swaps a.groups{1,3} <-> b.groups{0,2}
__device__ __forceinline__ void pl16(unsigned& a, unsigned& b) {
    asm volatile("v_permlane16_swap_b32 %0, %1" : "+v"(a), "+v"(b));
}

// ---------------- fused transpose+convert: 6 jobs, W[K,N] f32 -> WT[N,K] bf16 ----------------
__device__ __forceinline__ void tconv_tile(const float* __restrict__ W,
                                           __bf16* __restrict__ WT,
                                           int K, int N, int id, int nbx,
                                           __bf16 (*t)[65]) {
    int n0 = (id % nbx) * 64, k0 = (id / nbx) * 64;
    int tx = threadIdx.x & 63, ty = threadIdx.x >> 6;
#pragma unroll
    for (int r = ty; r < 64; r += 4)
        t[r][tx] = (__bf16)W[(size_t)(k0 + r) * N + n0 + tx];
    __syncthreads();
#pragma unroll
    for (int rr = ty; rr < 64; rr += 4)
        WT[(size_t)(n0 + rr) * K + k0 + tx] = t[tx][rr];
}

__global__ __launch_bounds__(256) void tconv6_kernel(
    const float* W0, __bf16* T0, const float* W1, __bf16* T1,
    const float* W2, __bf16* T2, const float* W3, __bf16* T3,
    const float* W4, __bf16* T4, const float* W5, __bf16* T5) {
    __shared__ __bf16 t[64][65];
    int id = blockIdx.x;
    // job block counts: 128,256,128,128,192,128 (cum 128,384,512,640,832,960)
    if (id < 128)      tconv_tile(W0, T0, 1024, 512,  id,       8,  t);
    else if (id < 384) tconv_tile(W1, T1, 1024, 1024, id - 128, 16, t);
    else if (id < 512) tconv_tile(W2, T2, 512,  1024, id - 384, 16, t);
    else if (id < 640) tconv_tile(W3, T3, 1024, 512,  id - 512, 8,  t);
    else if (id < 832) tconv_tile(W4, T4, 768,  1024, id - 640, 16, t);
    else               tconv_tile(W5, T5, 512,  1024, id - 832, 16, t);
}

// ---------------- LayerNorm body ----------------
template <int C>
__device__ __forceinline__ void ln_body(const float* __restrict__ xr,
                                        const float* __restrict__ g,
                                        const float* __restrict__ b,
                                        __bf16* __restrict__ orow,
                                        float* p1, float* p2) {
    constexpr int NP = (C == 1024) ? 4 : 3;
    float v[NP], s1 = 0.f, s2 = 0.f;
    if constexpr (C == 1024) {
        float4 f = *(const float4*)&xr[threadIdx.x * 4];
        v[0] = f.x; v[1] = f.y; v[2] = f.z; v[3] = f.w;
#pragma unroll
        for (int i = 0; i < 4; i++) { s1 += v[i]; s2 += v[i] * v[i]; }
    } else {
#pragma unroll
        for (int i = 0; i < 3; i++) {
            v[i] = xr[threadIdx.x + i * 256];
            s1 += v[i]; s2 += v[i] * v[i];
        }
    }
#pragma unroll
    for (int off = 1; off < 64; off <<= 1) {
        s1 += __shfl_xor(s1, off);
        s2 += __shfl_xor(s2, off);
    }
    int wave = threadIdx.x >> 6;
    if ((threadIdx.x & 63) == 0) { p1[wave] = s1; p2[wave] = s2; }
    __syncthreads();
    s1 = p1[0] + p1[1] + p1[2] + p1[3];
    s2 = p2[0] + p2[1] + p2[2] + p2[3];
    float mean = s1 / C;
    float rstd = rsqrtf(s2 / C - mean * mean + 1e-5f);
    if constexpr (C == 1024) {
        union { __bf16 h[4]; unsigned long long u; } pk;
#pragma unroll
        for (int i = 0; i < 4; i++) {
            int c = threadIdx.x * 4 + i;
            pk.h[i] = (__bf16)((v[i] - mean) * rstd * g[c] + b[c]);
        }
        *(unsigned long long*)&orow[threadIdx.x * 4] = pk.u;
    } else {
#pragma unroll
        for (int i = 0; i < 3; i++) {
            int c = threadIdx.x + i * 256;
            orow[c] = (__bf16)((v[i] - mean) * rstd * g[c] + b[c]);
        }
    }
}

// dual LayerNorm (shared row stats) for self-attn: x -> (g1,b1)->o1, (g2,b2)->o2
__global__ __launch_bounds__(256) void ln2_kernel(const float* __restrict__ x,
                                                  const float* __restrict__ g1,
                                                  const float* __restrict__ b1,
                                                  const float* __restrict__ g2,
                                                  const float* __restrict__ b2,
                                                  __bf16* __restrict__ o1,
                                                  __bf16* __restrict__ o2) {
    constexpr int C = 1024;
    int row = blockIdx.x;
    const float* xr = x + (size_t)row * C;
    float4 f = *(const float4*)&xr[threadIdx.x * 4];
    float v[4] = {f.x, f.y, f.z, f.w};
    float s1 = 0.f, s2 = 0.f;
#pragma unroll
    for (int i = 0; i < 4; i++) { s1 += v[i]; s2 += v[i] * v[i]; }
#pragma unroll
    for (int off = 1; off < 64; off <<= 1) {
        s1 += __shfl_xor(s1, off);
        s2 += __shfl_xor(s2, off);
    }
    __shared__ float p1[4], p2[4];
    int wave = threadIdx.x >> 6;
    if ((threadIdx.x & 63) == 0) { p1[wave] = s1; p2[wave] = s2; }
    __syncthreads();
    s1 = p1[0] + p1[1] + p1[2] + p1[3];
    s2 = p2[0] + p2[1] + p2[2] + p2[3];
    float mean = s1 / C;
    float rstd = rsqrtf(s2 / C - mean * mean + 1e-5f);
    union { __bf16 h[4]; unsigned long long u; } pk1, pk2;
#pragma unroll
    for (int i = 0; i < 4; i++) {
        int c = threadIdx.x * 4 + i;
        float nv = (v[i] - mean) * rstd;
        pk1.h[i] = (__bf16)(nv * g1[c] + b1[c]);
        pk2.h[i] = (__bf16)(nv * g2[c] + b2[c]);
    }
    *(unsigned long long*)&o1[(size_t)row * C + threadIdx.x * 4] = pk1.u;
    *(unsigned long long*)&o2[(size_t)row * C + threadIdx.x * 4] = pk2.u;
}

// fused cross-stage LNs: blocks [0,8192) -> ln1024(x1), [8192,10240) -> ln768(ctx)
__global__ __launch_bounds__(256) void ln_cross_kernel(
    const float* __restrict__ x1, const float* __restrict__ g1, const float* __restrict__ b1,
    __bf16* __restrict__ o1,
    const float* __restrict__ ctx, const float* __restrict__ g2, const float* __restrict__ b2,
    __bf16* __restrict__ o2, int rows1) {
    __shared__ float p1[4], p2[4];
    int id = blockIdx.x;
    if (id < rows1) {
        ln_body<1024>(x1 + (size_t)id * 1024, g1, b1, o1 + (size_t)id * 1024, p1, p2);
    } else {
        int row = id - rows1;
        ln_body<768>(ctx + (size_t)row * 768, g2, b2, o2 + (size_t)row * 768, p1, p2);
    }
}

// ---------------- GEMM core (BK=64): C[M,N] = A[M,K] @ BT[N,K]^T ----------------
// LDS per tile: 128 rows x 64 elems (16KB each), 16B chunks swizzled: chunk c at slot c^(r&7).
// EPI 0: store bf16 (acc*scale).  EPI 1: store f32 = acc + bias[col] + res[row,col]
template <int EPI>
__device__ __forceinline__ void gemm_core(const __bf16* __restrict__ A,
                                          const __bf16* __restrict__ BT,
                                          void* __restrict__ Cout,
                                          int N, int K, int bm, int bn,
                                          const float* __restrict__ bias,
                                          const float* __restrict__ res,
                                          float scale,
                                          __bf16* Al, __bf16* Bl) {
    int tid = threadIdx.x;
    int lane = tid & 63, wave = tid >> 6;
    int quad = lane >> 4, l15 = lane & 15;
    int wm = wave >> 1, wn = wave & 1;
    const __bf16* Ab = A + (size_t)(bm * 128) * K;
    const __bf16* Bb = BT + (size_t)(bn * 128) * K;
    f32x4 acc[4][4] = {};
    for (int k0 = 0; k0 < K; k0 += 64) {
#pragma unroll
        for (int j = 0; j < 4; j++) {
            int sbase = wave * 256 + j * 64;
            int s = sbase + lane;
            int r = s >> 3, c = (s & 7) ^ (r & 7);
            async16((char*)Al + sbase * 16, &Ab[(size_t)r * K + k0 + c * 8]);
            async16((char*)Bl + sbase * 16, &Bb[(size_t)r * K + k0 + c * 8]);
        }
        __syncthreads();
#pragma unroll
        for (int ks = 0; ks < 2; ks++) {
            bf16x8 a[4], b[4];
#pragma unroll
            for (int i = 0; i < 4; i++) {
                int row = wm * 64 + i * 16 + l15;
                a[i] = *(const bf16x8*)&Al[row * 64 + ((ks * 4 + quad) ^ (row & 7)) * 8];
            }
#pragma unroll
            for (int t = 0; t < 4; t++) {
                int row = wn * 64 + t * 16 + l15;
                b[t] = *(const bf16x8*)&Bl[row * 64 + ((ks * 4 + quad) ^ (row & 7)) * 8];
            }
#pragma unroll
            for (int i = 0; i < 4; i++)
#pragma unroll
                for (int t = 0; t < 4; t++) acc[i][t] = MFMA16(a[i], b[t], acc[i][t]);
        }
        __syncthreads();
    }
#pragma unroll
    for (int i = 0; i < 4; i++) {
#pragma unroll
        for (int t = 0; t < 4; t++) {
#pragma unroll
            for (int r = 0; r < 4; r++) {
                int row = bm * 128 + wm * 64 + i * 16 + quad * 4 + r;
                int col = bn * 128 + wn * 64 + t * 16 + l15;
                float vv = acc[i][t][r];
                if (EPI == 0) {
                    ((__bf16*)Cout)[(size_t)row * N + col] = (__bf16)(vv * scale);
                } else {
                    ((float*)Cout)[(size_t)row * N + col] =
                        vv + bias[col] + res[(size_t)row * N + col];
                }
            }
        }
    }
}

template <int EPI>
__global__ __launch_bounds__(256) void gemm_bt(const __bf16* __restrict__ A,
                                               const __bf16* __restrict__ BT,
                                               void* __restrict__ Cout,
                                               int M, int N, int K,
                                               const float* __restrict__ bias,
                                               const float* __restrict__ res) {
    __shared__ __align__(16) __bf16 Al[128 * 64];
    __shared__ __align__(16) __bf16 Bl[128 * 64];
    gemm_core<EPI>(A, BT, Cout, N, K, blockIdx.x, blockIdx.y, bias, res, 1.0f, Al, Bl);
}

// Fused 3-job GEMM (all EPI=0 bf16 out, per-job output scale).
__global__ __launch_bounds__(256) void gemm_fused3(
    const __bf16* A0, const __bf16* B0, __bf16* C0, int N0, int K0, int nbn0, float sc0,
    const __bf16* A1, const __bf16* B1, __bf16* C1, int N1, int K1, int nbn1, float sc1,
    const __bf16* A2, const __bf16* B2, __bf16* C2, int N2, int K2, int nbn2, float sc2,
    int c0, int c1) {
    __shared__ __align__(16) __bf16 Al[128 * 64];
    __shared__ __align__(16) __bf16 Bl[128 * 64];
    int id = blockIdx.x;
    if (id < c0) {
        gemm_core<0>(A0, B0, C0, N0, K0, id / nbn0, id % nbn0, nullptr, nullptr, sc0, Al, Bl);
    } else if (id < c1) {
        id -= c0;
        gemm_core<0>(A1, B1, C1, N1, K1, id / nbn1, id % nbn1, nullptr, nullptr, sc1, Al, Bl);
    } else {
        id -= c1;
        gemm_core<0>(A2, B2, C2, N2, K2, id / nbn2, id % nbn2, nullptr, nullptr, sc2, Al, Bl);
    }
}

// ---------------- flash attention v6: in-register P (cvt_pk + permlane swaps) ----------------
// v5 postmortem: still chain-latency-bound; the P LDS round-trip (write b64 -> lgkm ->
// read b128) sat mid-chain AND serialized the pair's two tiles (shared Ps region).
// v6: P never touches LDS. St output (q=l15, k=16t+4*quad+r) is redistributed to the
// PV A-operand layout (q=l15, k=32s+8*quad+j) entirely in-register:
//   per (s,u): A=pk_lo[2s], C=pk_lo[2s+1]; permlane32_swap(A,C); permlane16_swap(A,C)
//   -> A=[A@q0,A@q2,C@q0,C@q2]=word0, C=[A@q1,A@q3,C@q1,C@q3]=word2 (hi-pairs: words 1,3).
// Removes 12 LDS ops/tile + their waits, frees Ps (LDS 64KB), makes pair tiles truly
// independent. q pre-scaled by 0.125*log2(e) in its projection epilogue.
__global__ __launch_bounds__(256) void flash_kernel(const __bf16* __restrict__ q,
                                                    const __bf16* __restrict__ kb,
                                                    const __bf16* __restrict__ vt,
                                                    __bf16* __restrict__ out,
                                                    int n, int m) {
    __shared__ __align__(16) __bf16 Ks[2][2][64 * 64];   // [pair buf][tile in pair]
    __shared__ __align__(16) __bf16 VTs[2][2][64 * 64];
    int tid = threadIdx.x;
    int lane = tid & 63, w = tid >> 6;
    int quad = lane >> 4, l15 = lane & 15;
    int qt = blockIdx.x, h = blockIdx.y, b = blockIdx.z;
    const size_t BM = (size_t)gridDim.z * m;

    // Q fragments: this wave's 32 q-rows (2 u-tiles of 16)
    const __bf16* qbase = q + (size_t)(b * n + qt * 128 + w * 32) * 512 + h * 64;
    bf16x8 qf[2][2];
#pragma unroll
    for (int s = 0; s < 2; s++)
#pragma unroll
        for (int u = 0; u < 2; u++)
            qf[s][u] = *(const bf16x8*)&qbase[(u * 16 + l15) * 512 + s * 32 + quad * 8];

    // staging geometry: wave fills LDS slots [w*128, w*128+128) (two async16 per array)
    int s0 = w * 128 + lane, s1 = s0 + 64;
    int r0 = s0 >> 3, c0 = (s0 & 7) ^ (r0 & 7);
    int r1 = s1 >> 3, c1 = (s1 & 7) ^ (r1 & 7);
    const int sb0 = (w * 128) * 16, sb1 = sb0 + 64 * 16;  // wave-uniform LDS byte offsets
    const __bf16* ksrc0 = &kb[(size_t)(b * m + r0) * 512 + h * 64 + (size_t)c0 * 8];
    const __bf16* ksrc1 = &kb[(size_t)(b * m + r1) * 512 + h * 64 + (size_t)c1 * 8];
    const __bf16* vsrc0 = &vt[(size_t)(h * 64 + r0) * BM + b * m + (size_t)c0 * 8];
    const __bf16* vsrc1 = &vt[(size_t)(h * 64 + r1) * BM + b * m + (size_t)c1 * 8];
    const size_t kadv = (size_t)64 * 512;  // advance 64 K-rows per tile
    const int vadv = 64;                   // advance 64 VT-cols per tile

    f32x4 acc[2][4] = {};                  // O [u qtile][t2 dtile]
    float lp[2] = {0.f, 0.f};
    int npair = m / 128;

    // prologue: stage tiles 0,1 into pair buffer 0
#pragma unroll
    for (int tt = 0; tt < 2; tt++) {
        async16((char*)Ks[0][tt] + sb0, ksrc0);
        async16((char*)Ks[0][tt] + sb1, ksrc1);
        async16((char*)VTs[0][tt] + sb0, vsrc0);
        async16((char*)VTs[0][tt] + sb1, vsrc1);
        ksrc0 += kadv; ksrc1 += kadv; vsrc0 += vadv; vsrc1 += vadv;
    }

    for (int j = 0; j < npair; j++) {
        int pb = j & 1;
        // drains vmcnt -> pair buf[pb] ready; fences other waves off buf[pb^1]
        __syncthreads();
        if (j + 1 < npair) {
#pragma unroll
            for (int tt = 0; tt < 2; tt++) {
                async16((char*)Ks[pb ^ 1][tt] + sb0, ksrc0);
                async16((char*)Ks[pb ^ 1][tt] + sb1, ksrc1);
                async16((char*)VTs[pb ^ 1][tt] + sb0, vsrc0);
                async16((char*)VTs[pb ^ 1][tt] + sb1, vsrc1);
                ksrc0 += kadv; ksrc1 += kadv; vsrc0 += vadv; vsrc1 += vadv;
            }
        }

#pragma unroll
        for (int tt = 0; tt < 2; tt++) {
            const __bf16* Kc = Ks[pb][tt];
            const __bf16* Vc = VTs[pb][tt];

            // St = K @ Q^T; exp2; pack into bf16 pairs (kept in VGPRs)
            unsigned pkl[4][2], pkh[4][2];   // [t][u]
#pragma unroll
            for (int t = 0; t < 4; t++) {
                int krow = t * 16 + l15;
                bf16x8 ak0 = *(const bf16x8*)&Kc[krow * 64 + ((quad) ^ (krow & 7)) * 8];
                bf16x8 ak1 = *(const bf16x8*)&Kc[krow * 64 + ((4 + quad) ^ (krow & 7)) * 8];
                f32x4 sc[2] = {};
#pragma unroll
                for (int u = 0; u < 2; u++) {
                    sc[u] = MFMA16(ak0, qf[0][u], sc[u]);
                    sc[u] = MFMA16(ak1, qf[1][u], sc[u]);
                }
#pragma unroll
                for (int u = 0; u < 2; u++) {
                    float e0 = fast_exp2(sc[u][0]);
                    float e1 = fast_exp2(sc[u][1]);
                    float e2 = fast_exp2(sc[u][2]);
                    float e3 = fast_exp2(sc[u][3]);
                    lp[u] += (e0 + e1) + (e2 + e3);
                    pkl[t][u] = cvt_pk_bf16(e0, e1);
                    pkh[t][u] = cvt_pk_bf16(e2, e3);
                }
            }

            // in-register transpose to PV A-operand layout
            bf16x8 ap[2][2];   // [s][u]
#pragma unroll
            for (int s = 0; s < 2; s++)
#pragma unroll
                for (int u = 0; u < 2; u++) {
                    unsigned a = pkl[2 * s][u], c = pkl[2 * s + 1][u];
                    pl32(a, c); pl16(a, c);
                    unsigned bb = pkh[2 * s][u], d = pkh[2 * s + 1][u];
                    pl32(bb, d); pl16(bb, d);
                    union { unsigned wd[4]; bf16x8 v; } pu;
                    pu.wd[0] = a; pu.wd[1] = bb; pu.wd[2] = c; pu.wd[3] = d;
                    ap[s][u] = pu.v;
                }

            // O += P @ V (P in registers; V from LDS)
#pragma unroll
            for (int s = 0; s < 2; s++)
#pragma unroll
                for (int t2 = 0; t2 < 4; t2++) {
                    int drow = t2 * 16 + l15;
                    int jv = (s * 4 + quad) ^ (drow & 7);
                    bf16x8 bv = *(const bf16x8*)&Vc[drow * 64 + jv * 8];
#pragma unroll
                    for (int u = 0; u < 2; u++)
                        acc[u][t2] = MFMA16(ap[s][u], bv, acc[u][t2]);
                }
        }
    }

    // ---- epilogue: l-reduce over quads, scale, store ----
#pragma unroll
    for (int u = 0; u < 2; u++) {
        lp[u] += __shfl_xor(lp[u], 16);
        lp[u] += __shfl_xor(lp[u], 32);
    }
    float rinv0 = 1.0f / lp[0];
    float rinv1 = 1.0f / lp[1];
#pragma unroll
    for (int u = 0; u < 2; u++) {
#pragma unroll
        for (int r = 0; r < 4; r++) {
            float rl = __shfl(u == 0 ? rinv0 : rinv1, quad * 4 + r);
            int row = b * n + qt * 128 + w * 32 + u * 16 + quad * 4 + r;
#pragma unroll
            for (int t2 = 0; t2 < 4; t2++)
                out[(size_t)row * 512 + h * 64 + t2 * 16 + l15] =
                    (__bf16)(acc[u][t2][r] * rl);
        }
    }
}

extern "C" void kernel_launch(void* const* d_in, const int* in_sizes, int n_in,
                              void* d_out, int out_size, void* d_ws, size_t ws_size,
                              hipStream_t stream) {
    const float* x      = (const float*)d_in[0];
    const float* ctx    = (const float*)d_in[1];
    const float* sa_ng  = (const float*)d_in[2];
    const float* sa_nb  = (const float*)d_in[3];
    const float* sa_ncg = (const float*)d_in[4];
    const float* sa_ncb = (const float*)d_in[5];
    const float* sa_wq  = (const float*)d_in[6];
    const float* sa_wkv = (const float*)d_in[7];
    const float* sa_wo  = (const float*)d_in[8];
    const float* sa_bo  = (const float*)d_in[9];
    const float* ca_ng  = (const float*)d_in[10];
    const float* ca_nb  = (const float*)d_in[11];
    const float* ca_ncg = (const float*)d_in[12];
    const float* ca_ncb = (const float*)d_in[13];
    const float* ca_wq  = (const float*)d_in[14];
    const float* ca_wkv = (const float*)d_in[15];
    const float* ca_wo  = (const float*)d_in[16];
    const float* ca_bo  = (const float*)d_in[17];
    float* out = (float*)d_out;

    const int B = 4, N = 2048, M = 512, F = 1024, CF = 768, MID = 512;
    const int ROWS = B * N;   // 8192
    const int CROWS = B * M;  // 2048
    const float QSCALE = 0.125f * 1.4426950408889634f;  // attn scale * log2(e)

    char* ws = (char*)d_ws;
    size_t off = 0;
    auto alloc = [&](size_t bytes) {
        void* p = ws + off;
        off = (off + bytes + 255) & ~(size_t)255;
        return p;
    };
    __bf16* wqT   = (__bf16*)alloc((size_t)MID * F * 2);
    __bf16* wkvT  = (__bf16*)alloc((size_t)(2 * MID) * F * 2);
    __bf16* woT   = (__bf16*)alloc((size_t)F * MID * 2);
    __bf16* cwqT  = (__bf16*)alloc((size_t)MID * F * 2);
    __bf16* cwkvT = (__bf16*)alloc((size_t)(2 * MID) * CF * 2);
    __bf16* cwoT  = (__bf16*)alloc((size_t)F * MID * 2);
    __bf16* xn1   = (__bf16*)alloc((size_t)ROWS * F * 2);
    __bf16* xn2   = (__bf16*)alloc((size_t)ROWS * F * 2);
    __bf16* qb    = (__bf16*)alloc((size_t)ROWS * MID * 2);
    __bf16* kb    = (__bf16*)alloc((size_t)ROWS * MID * 2);
    __bf16* vt    = (__bf16*)alloc((size_t)MID * ROWS * 2);
    __bf16* ao    = (__bf16*)alloc((size_t)ROWS * MID * 2);
    float*  x1    = (float*)alloc((size_t)ROWS * F * 4);
    (void)ws_size; (void)in_sizes; (void)n_in; (void)out_size;

    dim3 blk(256);

    tconv6_kernel<<<dim3(960), blk, 0, stream>>>(
        sa_wq, wqT, sa_wkv, wkvT, sa_wo, woT, ca_wq, cwqT, ca_wkv, cwkvT, ca_wo, cwoT);

    // ---- self-attention ----
    ln2_kernel<<<dim3(ROWS), blk, 0, stream>>>(x, sa_ng, sa_nb, sa_ncg, sa_ncb, xn1, xn2);
    {
        int c0 = (ROWS / 128) * (MID / 128);          // q: 256
        int c1 = c0 + (ROWS / 128) * (MID / 128);     // k: 256
        int c2 = c1 + (MID / 128) * (ROWS / 128);     // vt: 256
        gemm_fused3<<<dim3(c2), blk, 0, stream>>>(
            xn1, wqT, qb, MID, F, MID / 128, QSCALE,
            xn2, wkvT, kb, MID, F, MID / 128, 1.0f,
            wkvT + (size_t)MID * F, xn2, vt, ROWS, F, ROWS / 128, 1.0f,
            c0, c1);
    }
    flash_kernel<<<dim3(N / 128, 8, B), blk, 0, stream>>>(qb, kb, vt, ao, N, N);
    gemm_bt<1><<<dim3(ROWS / 128, F / 128), blk, 0, stream>>>(
        ao, woT, x1, ROWS, F, MID, sa_bo, x);

    // ---- cross-attention ----
    ln_cross_kernel<<<dim3(ROWS + CROWS), blk, 0, stream>>>(
        x1, ca_ng, ca_nb, xn1, ctx, ca_ncg, ca_ncb, xn2, ROWS);
    {
        int c0 = (ROWS / 128) * (MID / 128);          // q: 256
        int c1 = c0 + (CROWS / 128) * (MID / 128);    // k: 64
        int c2 = c1 + (MID / 128) * (CROWS / 128);    // vt: 64
        gemm_fused3<<<dim3(c2), blk, 0, stream>>>(
            xn1, cwqT, qb, MID, F, MID / 128, QSCALE,
            xn2, cwkvT, kb, MID, CF, MID / 128, 1.0f,
            cwkvT + (size_t)MID * CF, xn2, vt, CROWS, CF, CROWS / 128, 1.0f,
            c0, c1);
    }
    flash_kernel<<<dim3(N / 128, 8, B), blk, 0, stream>>>(qb, kb, vt, ao, N, M);
    gemm_bt<1><<<dim3(ROWS / 128, F / 128), blk, 0, stream>>>(
        ao, cwoT, out, ROWS, F, MID, ca_bo, x1);
}